// Round 1
// baseline (361.316 us; speedup 1.0000x reference)
//
#include <hip/hip_runtime.h>

typedef _Float16 half8 __attribute__((ext_vector_type(8)));
typedef float f32x4 __attribute__((ext_vector_type(4)));

#define SA1 296   // LDS act stride (elements) for layer 1 (K=292 -> pad 296)
#define SA2 264   // LDS act stride for layers 2..5 (K=256 + 8 pad)

// ---------------------------------------------------------------------------
// Prep: features -> featT [H*W][32] fp16 ; weights -> Wt[n][k] fp16 transposed
// W1 columns permuted: col = k*32 + c  <->  w1 row c*9 + k ; cols 288..291 =
// rel0,rel1,cell0,cell1 ; cols 292..319 = 0.
// ---------------------------------------------------------------------------
__global__ void liif_prep(const float* __restrict__ feat,
                          const float* __restrict__ w1, const float* __restrict__ w2,
                          const float* __restrict__ w3, const float* __restrict__ w4,
                          const float* __restrict__ w5,
                          _Float16* __restrict__ featT,
                          _Float16* __restrict__ wt1, _Float16* __restrict__ wt2,
                          _Float16* __restrict__ wt3, _Float16* __restrict__ wt4,
                          _Float16* __restrict__ wt5) {
  int i = blockIdx.x * 256 + threadIdx.x;
  if (i < 2097152) {                       // featT[px*32+c] = feat[c*65536+px]
    int c = i >> 16, px = i & 65535;
    featT[px * 32 + c] = (_Float16)feat[i];
    return;
  }
  i -= 2097152;
  if (i < 81920) {                         // wt1: [256][320]
    int n = i / 320, kcol = i % 320;
    float v = 0.f;
    if (kcol < 288) {
      int k = kcol >> 5, c = kcol & 31;
      v = w1[(c * 9 + k) * 256 + n];
    } else if (kcol < 292) {
      v = w1[kcol * 256 + n];
    }
    wt1[i] = (_Float16)v;
    return;
  }
  i -= 81920;
  if (i < 196608) {                        // wt2..wt4: [256][256] transposed
    int li = i >> 16, r = i & 65535;
    int n = r >> 8, k = r & 255;
    const float* w = (li == 0) ? w2 : ((li == 1) ? w3 : w4);
    _Float16* wt = (li == 0) ? wt2 : ((li == 1) ? wt3 : wt4);
    wt[r] = (_Float16)w[k * 256 + n];
    return;
  }
  i -= 196608;
  if (i < 4096) {                          // wt5: [16][256], rows 3..15 zero
    int n = i >> 8, k = i & 255;
    wt5[i] = (n < 3) ? (_Float16)w5[k * 3 + n] : (_Float16)0.f;
  }
}

// ---------------------------------------------------------------------------
// One MLP layer: acc[4][4] += act(64 x K, LDS) @ Wt^T(K x 256, global/L2).
// A-frag: lane holds act[m=lane&15][k=quad*8+j]; B-frag: Wt[n=lane&15][k..].
// No barriers inside (B streams from L2; weights are block-invariant).
// ---------------------------------------------------------------------------
template <int SA, int KW, int NSTEPS, bool LAST>
__device__ __forceinline__ void layer_mm(const _Float16* __restrict__ wt,
                                         f32x4 acc[4][4],
                                         const _Float16* sA, int tid) {
  if (LAST && tid >= 64) return;           // only wave 0 computes the 3-wide head
  const int lane = tid & 63;
  const int nw = LAST ? 0 : (tid >> 6);
  const int ln = lane & 15, q8 = (lane >> 4) * 8;
  const _Float16* wbase = wt + (nw * 64 + ln) * KW + q8;
  const _Float16* abase = sA + ln * SA + q8;
#pragma unroll
  for (int st = 0; st < NSTEPS; ++st) {
    const int kc = st * 32;
    half8 a[4];
#pragma unroll
    for (int mt = 0; mt < 4; ++mt)
      a[mt] = *(const half8*)(abase + mt * 16 * SA + kc);
    half8 b[4];
#pragma unroll
    for (int nt = 0; nt < (LAST ? 1 : 4); ++nt)
      b[nt] = *(const half8*)(wbase + nt * 16 * KW + kc);
#pragma unroll
    for (int nt = 0; nt < (LAST ? 1 : 4); ++nt)
#pragma unroll
      for (int mt = 0; mt < 4; ++mt)
        acc[mt][nt] =
            __builtin_amdgcn_mfma_f32_16x16x32_f16(a[mt], b[nt], acc[mt][nt], 0, 0, 0);
  }
}

// bias + ReLU, write fp16 act back to LDS at stride SA2. C/D layout:
// row m = quad*4 + reg, col n = lane&15  (m89-verified mapping).
__device__ __forceinline__ void epilogue_relu(f32x4 acc[4][4], _Float16* sA,
                                              const float* __restrict__ bias, int tid) {
  __syncthreads();                          // all waves done reading act
  const int lane = tid & 63, nw = tid >> 6;
  const int ln = lane & 15, q4 = (lane >> 4) * 4;
#pragma unroll
  for (int nt = 0; nt < 4; ++nt) {
    const int n = nw * 64 + nt * 16 + ln;
    const float bv = bias[n];
#pragma unroll
    for (int mt = 0; mt < 4; ++mt) {
#pragma unroll
      for (int r = 0; r < 4; ++r) {
        float v = acc[mt][nt][r] + bv;
        acc[mt][nt][r] = 0.f;
        v = fmaxf(v, 0.f);
        sA[(mt * 16 + q4 + r) * SA2 + n] = (_Float16)v;
      }
    }
  }
  __syncthreads();                          // act visible before next layer reads
}

// ---------------------------------------------------------------------------
// Main fused kernel: 1 block = 64 rows = 16 queries x 4 shifts.
// ---------------------------------------------------------------------------
__global__ __launch_bounds__(256, 2) void liif_main(
    const _Float16* __restrict__ featT,
    const float* __restrict__ loc, const float* __restrict__ cell,
    const float* __restrict__ b1, const float* __restrict__ b2,
    const float* __restrict__ b3, const float* __restrict__ b4,
    const float* __restrict__ b5,
    const _Float16* __restrict__ wt1, const _Float16* __restrict__ wt2,
    const _Float16* __restrict__ wt3, const _Float16* __restrict__ wt4,
    const _Float16* __restrict__ wt5,
    float* __restrict__ out) {
  __shared__ __align__(16) _Float16 sAct[64 * SA1 + 32];  // + overrun guard
  __shared__ float sWgt[64];
  __shared__ float sPred[64 * 4];
  __shared__ int sIy[64], sIx[64];
  __shared__ float sRel0[64], sRel1[64], sC0[64], sC1[64], sArea[64];

  const int tid = threadIdx.x;
  const int blk = blockIdx.x;
  const int r0 = blk * 64, q0 = blk * 16;

  // ---- per-row params (row r = q*4 + s) ----
  if (tid < 64) {
    const int r = r0 + tid, q = r >> 2, s = r & 3;
    const float loc0 = loc[q * 2 + 0], loc1 = loc[q * 2 + 1];
    const float shy = (s & 2) ? 1.f : -1.f;
    const float shx = (s & 1) ? 1.f : -1.f;
    const float rxy = 1.f / 256.f;
    float l0 = __fadd_rn(loc0 + shy * rxy, 1e-6f);
    float l1 = __fadd_rn(loc1 + shx * rxy, 1e-6f);
    const float lo = -1.f + 1e-6f, hi = 1.f - 1e-6f;
    l0 = fminf(fmaxf(l0, lo), hi);
    l1 = fminf(fmaxf(l1, lo), hi);
    int iy = (int)rintf(__fmul_rn(__fadd_rn(__fmul_rn(__fadd_rn(l0, 1.f), 256.f), -1.f), 0.5f));
    int ix = (int)rintf(__fmul_rn(__fadd_rn(__fmul_rn(__fadd_rn(l1, 1.f), 256.f), -1.f), 0.5f));
    iy = min(max(iy, 0), 255);
    ix = min(max(ix, 0), 255);
    const float qy = -1.f + (float)(2 * iy + 1) * (1.f / 256.f);
    const float qx = -1.f + (float)(2 * ix + 1) * (1.f / 256.f);
    const float rel0v = __fmul_rn(__fsub_rn(loc0, qy), 256.f);
    const float rel1v = __fmul_rn(__fsub_rn(loc1, qx), 256.f);
    sIy[tid] = iy; sIx[tid] = ix;
    sRel0[tid] = rel0v; sRel1[tid] = rel1v;
    sArea[tid] = fabsf(rel0v * rel1v) + 1e-9f;
    sC0[tid] = cell[q * 2 + 0] * 256.f;
    sC1[tid] = cell[q * 2 + 1] * 256.f;
  }
  __syncthreads();

  // ---- combine weights: w[q*4+s] = area[q*4+(3-s)] / tot ----
  if (tid < 16) {
    const int b4i = tid * 4;
    const float a0 = sArea[b4i], a1 = sArea[b4i + 1], a2 = sArea[b4i + 2], a3 = sArea[b4i + 3];
    const float tot = a0 + a1 + a2 + a3;
    sWgt[b4i + 0] = a3 / tot;
    sWgt[b4i + 1] = a2 / tot;
    sWgt[b4i + 2] = a1 / tot;
    sWgt[b4i + 3] = a0 / tot;
  }

  // ---- gather: X row layout col = k*32 + c (k = 3x3 pixel, c = channel) ----
  {
    const int row = tid >> 2, part = tid & 3;
    const int iy = sIy[row], ix = sIx[row];
    const int y0 = (iy == 0) ? 1 : iy - 1;
    const int y2 = (iy == 255) ? 254 : iy + 1;
    const int x0 = (ix == 0) ? 1 : ix - 1;
    const int x2 = (ix == 255) ? 254 : ix + 1;
    _Float16* arow = sAct + row * SA1;
    const int pofs = part * 8;
#pragma unroll
    for (int k = 0; k < 9; ++k) {
      const int dy = k / 3, dx = k % 3;
      const int y = (dy == 0) ? y0 : ((dy == 1) ? iy : y2);
      const int x = (dx == 0) ? x0 : ((dx == 1) ? ix : x2);
      const half8 v = *(const half8*)(featT + (y * 256 + x) * 32 + pofs);
      *(half8*)(arow + k * 32 + pofs) = v;
    }
    if (part == 0) {
      arow[288] = (_Float16)sRel0[row];
      arow[289] = (_Float16)sRel1[row];
      arow[290] = (_Float16)sC0[row];
      arow[291] = (_Float16)sC1[row];
      arow[292] = (_Float16)0.f; arow[293] = (_Float16)0.f;
      arow[294] = (_Float16)0.f; arow[295] = (_Float16)0.f;
    }
  }
  if (tid < 32) sAct[64 * SA1 + tid] = (_Float16)0.f;  // guard for k-step 9 overrun

  f32x4 acc[4][4];
#pragma unroll
  for (int mt = 0; mt < 4; ++mt)
#pragma unroll
    for (int nt = 0; nt < 4; ++nt)
      acc[mt][nt] = (f32x4){0.f, 0.f, 0.f, 0.f};

  __syncthreads();  // gather visible

  // ---- MLP ----
  layer_mm<SA1, 320, 10, false>(wt1, acc, sAct, tid);  // k-step 9: A garbage x W=0
  epilogue_relu(acc, sAct, b1, tid);
  layer_mm<SA2, 256, 8, false>(wt2, acc, sAct, tid);
  epilogue_relu(acc, sAct, b2, tid);
  layer_mm<SA2, 256, 8, false>(wt3, acc, sAct, tid);
  epilogue_relu(acc, sAct, b3, tid);
  layer_mm<SA2, 256, 8, false>(wt4, acc, sAct, tid);
  epilogue_relu(acc, sAct, b4, tid);
  layer_mm<SA2, 256, 8, true>(wt5, acc, sAct, tid);

  // ---- head + area-weighted combine ----
  if (tid < 64) {
    const int ln = tid & 15, q4v = (tid >> 4) * 4;
    if (ln < 3) {
      const float bv = b5[ln];
#pragma unroll
      for (int mt = 0; mt < 4; ++mt)
#pragma unroll
        for (int r = 0; r < 4; ++r)
          sPred[(mt * 16 + q4v + r) * 4 + ln] = acc[mt][0][r] + bv;
    }
  }
  __syncthreads();
  if (tid < 48) {
    const int ql = tid / 3, c = tid - ql * 3;
    float sum = 0.f;
#pragma unroll
    for (int sh = 0; sh < 4; ++sh)
      sum += sPred[(ql * 4 + sh) * 4 + c] * sWgt[ql * 4 + sh];
    out[(q0 + ql) * 3 + c] = sum;
  }
}

// ---------------------------------------------------------------------------
extern "C" void kernel_launch(void* const* d_in, const int* in_sizes, int n_in,
                              void* d_out, int out_size, void* d_ws, size_t ws_size,
                              hipStream_t stream) {
  (void)in_sizes; (void)n_in; (void)out_size; (void)ws_size;
  const float* feat = (const float*)d_in[0];
  const float* loc  = (const float*)d_in[1];
  const float* cell = (const float*)d_in[2];
  const float* w1 = (const float*)d_in[3];  const float* b1 = (const float*)d_in[4];
  const float* w2 = (const float*)d_in[5];  const float* b2 = (const float*)d_in[6];
  const float* w3 = (const float*)d_in[7];  const float* b3 = (const float*)d_in[8];
  const float* w4 = (const float*)d_in[9];  const float* b4 = (const float*)d_in[10];
  const float* w5 = (const float*)d_in[11]; const float* b5 = (const float*)d_in[12];

  char* ws = (char*)d_ws;
  _Float16* featT = (_Float16*)(ws);                    // 4,194,304 B
  _Float16* wt1 = (_Float16*)(ws + 4194304);            //   163,840 B
  _Float16* wt2 = (_Float16*)(ws + 4358144);            //   131,072 B
  _Float16* wt3 = (_Float16*)(ws + 4489216);            //   131,072 B
  _Float16* wt4 = (_Float16*)(ws + 4620288);            //   131,072 B
  _Float16* wt5 = (_Float16*)(ws + 4751360);            //     8,192 B

  liif_prep<<<9296, 256, 0, stream>>>(feat, w1, w2, w3, w4, w5,
                                      featT, wt1, wt2, wt3, wt4, wt5);
  liif_main<<<4096, 256, 0, stream>>>(featT, loc, cell, b1, b2, b3, b4, b5,
                                      wt1, wt2, wt3, wt4, wt5, (float*)d_out);
}